// Round 1
// baseline (11244.333 us; speedup 1.0000x reference)
//
#include <hip/hip_runtime.h>
#include <math.h>

// ---------------- constants ----------------
#define SEQ 128
#define BATCH 256
#define INPUT 300
#define HIDDEN 1024
#define NGATES 4096          // 4*HIDDEN
#define KTOT 1324            // INPUT + HIDDEN
#define LINEARN 1024

#define BM 64
#define BN 64
#define BK 16
#define LDP 68               // padded LDS leading dim (keeps float4 16B-aligned, 2-way max conflicts)

__device__ __forceinline__ float sigf(float x)      { return 1.f / (1.f + __expf(-x)); }
__device__ __forceinline__ float tanhfast(float x)  { return 2.f / (1.f + __expf(-2.f * x)) - 1.f; }

// ---------------- zero h,c ----------------
__global__ __launch_bounds__(256) void zero_ws(float4* p, int n4) {
  int i = blockIdx.x * 256 + threadIdx.x;
  if (i < n4) p[i] = make_float4(0.f, 0.f, 0.f, 0.f);
}

// ---------------- generic C = A * B^T + bias ----------------
// A row m: k<Kx -> Ax[m*Kx + k], else Ah[m*Kh_stride + (k-Kx)]
// B row n: k<Kx -> B1[n*Kx + k], else B2[n*Kh_stride + (k-Kx)]
// Kx, Ktot, strides all multiples of 4 so float4 never crosses a region boundary.
__global__ __launch_bounds__(256) void gemm_bt(
    const float* __restrict__ Ax, int Kx,
    const float* __restrict__ Ah, int Kh_stride,
    const float* __restrict__ B1, const float* __restrict__ B2,
    const float* __restrict__ bias1, const float* __restrict__ bias2,
    int Ktot, int N, float* __restrict__ C)
{
  __shared__ float sA[BK * LDP];
  __shared__ float sB[BK * LDP];
  const int t  = threadIdx.x;
  const int tx = t & 15;         // 0..15 -> N micro
  const int ty = t >> 4;         // 0..15 -> M micro
  const int r  = t >> 2;         // 0..63 -> tile row for staging
  const int c4 = (t & 3) << 2;   // 0,4,8,12 -> k offset for staging
  const int m0 = blockIdx.y * BM;
  const int n0 = blockIdx.x * BN;

  float acc[4][4] = {{0.f}};

  for (int k0 = 0; k0 < Ktot; k0 += BK) {
    const int k = k0 + c4;
    float4 av = make_float4(0.f, 0.f, 0.f, 0.f);
    float4 bv = make_float4(0.f, 0.f, 0.f, 0.f);
    {
      const int mA = m0 + r;
      if (k + 3 < Kx)      av = *(const float4*)(Ax + (size_t)mA * Kx + k);
      else if (k < Ktot)   av = *(const float4*)(Ah + (size_t)mA * Kh_stride + (k - Kx));
      const int nB = n0 + r;
      if (k + 3 < Kx)      bv = *(const float4*)(B1 + (size_t)nB * Kx + k);
      else if (k < Ktot)   bv = *(const float4*)(B2 + (size_t)nB * Kh_stride + (k - Kx));
    }
    __syncthreads();
    sA[(c4 + 0) * LDP + r] = av.x;  sA[(c4 + 1) * LDP + r] = av.y;
    sA[(c4 + 2) * LDP + r] = av.z;  sA[(c4 + 3) * LDP + r] = av.w;
    sB[(c4 + 0) * LDP + r] = bv.x;  sB[(c4 + 1) * LDP + r] = bv.y;
    sB[(c4 + 2) * LDP + r] = bv.z;  sB[(c4 + 3) * LDP + r] = bv.w;
    __syncthreads();
#pragma unroll
    for (int kk = 0; kk < BK; ++kk) {
      const float4 a = *(const float4*)&sA[kk * LDP + ty * 4];
      const float4 b = *(const float4*)&sB[kk * LDP + tx * 4];
      acc[0][0] += a.x * b.x; acc[0][1] += a.x * b.y; acc[0][2] += a.x * b.z; acc[0][3] += a.x * b.w;
      acc[1][0] += a.y * b.x; acc[1][1] += a.y * b.y; acc[1][2] += a.y * b.z; acc[1][3] += a.y * b.w;
      acc[2][0] += a.z * b.x; acc[2][1] += a.z * b.y; acc[2][2] += a.z * b.z; acc[2][3] += a.z * b.w;
      acc[3][0] += a.w * b.x; acc[3][1] += a.w * b.y; acc[3][2] += a.w * b.z; acc[3][3] += a.w * b.w;
    }
  }

  float bias[4];
#pragma unroll
  for (int j = 0; j < 4; ++j) {
    const int n = n0 + tx * 4 + j;
    float bsum = 0.f;
    if (bias1) bsum += bias1[n];
    if (bias2) bsum += bias2[n];
    bias[j] = bsum;
  }
#pragma unroll
  for (int i = 0; i < 4; ++i) {
    const int m = m0 + ty * 4 + i;
    float4 o;
    o.x = acc[i][0] + bias[0];
    o.y = acc[i][1] + bias[1];
    o.z = acc[i][2] + bias[2];
    o.w = acc[i][3] + bias[3];
    *(float4*)(C + (size_t)m * N + n0 + tx * 4) = o;
  }
}

// ---------------- LSTM cell elementwise ----------------
// gates laid out [BATCH][4096] fp32; i,f,g,o chunks of 1024.
__global__ __launch_bounds__(256) void lstm_cell(
    const float4* __restrict__ gates, float4* __restrict__ c, float4* __restrict__ h)
{
  const int idx = blockIdx.x * 256 + threadIdx.x;    // over 65536 float4s
  const int b = idx >> 8;                            // batch row
  const int j = idx & 255;                           // float4 col within HIDDEN
  const int base = b * 1024;                         // row = 1024 float4s
  const float4 gi = gates[base + j];
  const float4 gf = gates[base + 256 + j];
  const float4 gg = gates[base + 512 + j];
  const float4 go = gates[base + 768 + j];
  float4 cv = c[idx];

  float4 cn, hn;
  cn.x = sigf(gf.x) * cv.x + sigf(gi.x) * tanhfast(gg.x);
  cn.y = sigf(gf.y) * cv.y + sigf(gi.y) * tanhfast(gg.y);
  cn.z = sigf(gf.z) * cv.z + sigf(gi.z) * tanhfast(gg.z);
  cn.w = sigf(gf.w) * cv.w + sigf(gi.w) * tanhfast(gg.w);
  hn.x = sigf(go.x) * tanhfast(cn.x);
  hn.y = sigf(go.y) * tanhfast(cn.y);
  hn.z = sigf(go.z) * tanhfast(cn.z);
  hn.w = sigf(go.w) * tanhfast(cn.w);
  c[idx] = cn;
  h[idx] = hn;
}

// ---------------- BN stats per column ----------------
__global__ __launch_bounds__(64) void bn_stats(
    const float* __restrict__ z, float* __restrict__ mean, float* __restrict__ rstd)
{
  const int n = blockIdx.x;
  const int t = threadIdx.x;
  float s = 0.f, s2 = 0.f;
  for (int r = t; r < BATCH; r += 64) {
    const float v = z[(size_t)r * LINEARN + n];
    s += v; s2 += v * v;
  }
#pragma unroll
  for (int off = 32; off > 0; off >>= 1) {
    s  += __shfl_down(s,  off, 64);
    s2 += __shfl_down(s2, off, 64);
  }
  if (t == 0) {
    const float m = s * (1.f / BATCH);
    mean[n] = m;
    rstd[n] = rsqrtf(s2 * (1.f / BATCH) - m * m + 1e-5f);
  }
}

// ---------------- head: BN apply + relu + dot(W2) + 3*sigmoid ----------------
__global__ __launch_bounds__(256) void head_out(
    const float* __restrict__ z, const float* __restrict__ mean, const float* __restrict__ rstd,
    const float* __restrict__ gamma, const float* __restrict__ beta,
    const float* __restrict__ W2, const float* __restrict__ b2, float* __restrict__ out)
{
  const int b = blockIdx.x;
  const int t = threadIdx.x;
  float acc = 0.f;
  for (int n = t; n < LINEARN; n += 256) {
    float v = (z[(size_t)b * LINEARN + n] - mean[n]) * rstd[n] * gamma[n] + beta[n];
    v = fmaxf(v, 0.f);
    acc += v * W2[n];
  }
#pragma unroll
  for (int off = 32; off > 0; off >>= 1) acc += __shfl_down(acc, off, 64);
  __shared__ float ls[4];
  if ((t & 63) == 0) ls[t >> 6] = acc;
  __syncthreads();
  if (t == 0) {
    const float tot = ls[0] + ls[1] + ls[2] + ls[3] + b2[0];
    out[b] = 3.f / (1.f + __expf(-tot));
  }
}

// ---------------- launch ----------------
extern "C" void kernel_launch(void* const* d_in, const int* in_sizes, int n_in,
                              void* d_out, int out_size, void* d_ws, size_t ws_size,
                              hipStream_t stream) {
  const float* x     = (const float*)d_in[0];   // [128,256,300]
  const float* W_ih  = (const float*)d_in[1];   // [4096,300]
  const float* W_hh  = (const float*)d_in[2];   // [4096,1024]
  const float* b_ih  = (const float*)d_in[3];   // [4096]
  const float* b_hh  = (const float*)d_in[4];   // [4096]
  const float* W1    = (const float*)d_in[5];   // [1024,1024]
  const float* b1    = (const float*)d_in[6];   // [1024]
  const float* gamma = (const float*)d_in[7];   // [1024]
  const float* beta  = (const float*)d_in[8];   // [1024]
  const float* W2    = (const float*)d_in[9];   // [1,1024]
  const float* b2    = (const float*)d_in[10];  // [1]
  float* out = (float*)d_out;

  float* ws    = (float*)d_ws;
  float* h     = ws;                    // 256*1024
  float* c     = ws + 262144;           // 256*1024
  float* gates = ws + 524288;           // 256*4096
  float* z     = ws + 1572864;          // 256*1024
  float* mean  = ws + 1835008;          // 1024
  float* rstd  = ws + 1836032;          // 1024

  // zero h and c (ws is poisoned before every call)
  zero_ws<<<512, 256, 0, stream>>>((float4*)ws, 131072);

  for (int t = 0; t < SEQ; ++t) {
    const float* xt = x + (size_t)t * BATCH * INPUT;
    gemm_bt<<<dim3(NGATES / BN, BATCH / BM), 256, 0, stream>>>(
        xt, INPUT, h, HIDDEN, W_ih, W_hh, b_ih, b_hh, KTOT, NGATES, gates);
    lstm_cell<<<256, 256, 0, stream>>>((const float4*)gates, (float4*)c, (float4*)h);
  }

  // head linear: z = h @ W1^T + b1
  gemm_bt<<<dim3(LINEARN / BN, BATCH / BM), 256, 0, stream>>>(
      nullptr, 0, h, HIDDEN, nullptr, W1, b1, nullptr, HIDDEN, LINEARN, z);
  bn_stats<<<LINEARN, 64, 0, stream>>>(z, mean, rstd);
  head_out<<<BATCH, 256, 0, stream>>>(z, mean, rstd, gamma, beta, W2, b2, out);
}

// Round 2
// 4345.770 us; speedup vs baseline: 2.5874x; 2.5874x over previous
//
#include <hip/hip_runtime.h>
#include <math.h>

// ---------------- constants ----------------
#define SEQ 128
#define BATCH 256
#define INPUT 300
#define HIDDEN 1024
#define NG 4096              // 4*HIDDEN, gate-interleaved: n' = 4*j + gate
#define KH 1024              // h part of K (first)
#define KXP 320              // x part padded 300->320
#define KT 1344              // KH + KXP
#define NKT 42               // KT/32 k-tiles
#define KTH 32               // KH/32 k-tiles from h
#define LINEARN 1024

typedef __attribute__((ext_vector_type(8))) short short8;
typedef __attribute__((ext_vector_type(4))) float floatx4;

__device__ __forceinline__ float sigf(float x)     { return 1.f / (1.f + __expf(-x)); }
__device__ __forceinline__ float tanhfast(float x) { return 2.f / (1.f + __expf(-2.f * x)) - 1.f; }

__device__ __forceinline__ unsigned short bf16_rne(float f) {
  unsigned u = __float_as_uint(f);
  u += 0x7FFFu + ((u >> 16) & 1u);
  return (unsigned short)(u >> 16);
}
__device__ __forceinline__ float bf16f(unsigned short s) {
  return __uint_as_float(((unsigned)s) << 16);
}

// ---------------- zero ----------------
__global__ __launch_bounds__(256) void zero_ws(float4* p, int n4) {
  int i = blockIdx.x * 256 + threadIdx.x;
  if (i < n4) p[i] = make_float4(0.f, 0.f, 0.f, 0.f);
}

// ---------------- weight pack: gate-interleave + pad + bf16 hi/lo split ----------------
// Wp[n'][k], n' = 4*j + g  (source row g*1024+j); k<1024 -> W_hh, 1024<=k<1324 -> W_ih, else 0.
__global__ __launch_bounds__(256) void pack_w(
    const float* __restrict__ W_ih, const float* __restrict__ W_hh,
    unsigned short* __restrict__ Wph, unsigned short* __restrict__ Wpl)
{
  int id = blockIdx.x * 256 + threadIdx.x;
  if (id >= NG * KT) return;
  int n = id / KT;
  int k = id - n * KT;
  int j = n >> 2, g = n & 3;
  int srow = g * HIDDEN + j;
  float w = 0.f;
  if (k < KH) w = W_hh[(size_t)srow * HIDDEN + k];
  else if (k - KH < INPUT) w = W_ih[(size_t)srow * INPUT + (k - KH)];
  unsigned short hi = bf16_rne(w);
  Wph[id] = hi;
  Wpl[id] = bf16_rne(w - bf16f(hi));
}

__global__ __launch_bounds__(256) void pack_bias(
    const float* __restrict__ b_ih, const float* __restrict__ b_hh,
    float* __restrict__ biasp)
{
  int n = blockIdx.x * 256 + threadIdx.x;   // n' index
  if (n >= NG) return;
  int j = n >> 2, g = n & 3;
  int s = g * HIDDEN + j;
  biasp[n] = b_ih[s] + b_hh[s];
}

// ---------------- fused LSTM step: gates GEMM (split-bf16 MFMA) + cell ----------------
// grid (64 jtiles, 4 mtiles), 256 threads. Block computes C[64 m][64 n'] = 16 j x 4 gates,
// then the cell update for its (m, j) cells. h double-buffered (read r / write w).
__global__ __launch_bounds__(256) void lstm_step(
    const float* __restrict__ xt,               // [256][300]
    const unsigned short* __restrict__ h_hi_r,  // [256][1024]
    const unsigned short* __restrict__ h_lo_r,
    const unsigned short* __restrict__ Wph,     // [4096][1344]
    const unsigned short* __restrict__ Wpl,
    const float* __restrict__ biasp,            // [4096]
    float* __restrict__ cst,                    // [256][1024] fp32 cell state
    unsigned short* __restrict__ h_hi_w,
    unsigned short* __restrict__ h_lo_w,
    float* __restrict__ h_f32)                  // [256][1024]
{
  // staging: 4 tiles of [64 rows][32 k] bf16, row stride 40 (2-way bank max = free)
  __shared__ short sb[4 * 2560];
  short* sAh = sb;
  short* sAl = sb + 2560;
  short* sBh = sb + 5120;
  short* sBl = sb + 7680;

  const int t    = threadIdx.x;
  const int lane = t & 63;
  const int wave = t >> 6;
  const int wm   = (wave >> 1) * 32;    // wave m origin in tile
  const int wn   = (wave & 1) * 32;     // wave n origin in tile
  const int col  = lane & 15;
  const int quad = lane >> 4;
  const int r    = t >> 2;              // staging row 0..63
  const int k8   = (t & 3) * 8;         // staging k offset {0,8,16,24}
  const int m0   = blockIdx.y * 64;
  const int n0   = blockIdx.x * 64;
  const int j0   = blockIdx.x * 16;

  floatx4 acc[2][2];
#pragma unroll
  for (int i = 0; i < 2; ++i)
#pragma unroll
    for (int jj = 0; jj < 2; ++jj)
      acc[i][jj] = (floatx4){0.f, 0.f, 0.f, 0.f};

  for (int kt = 0; kt < NKT; ++kt) {
    // ---- global loads (issued before barrier, overlap prior MFMA) ----
    uint4 avh, avl, bvh, bvl;
    if (kt < KTH) {
      const int ka = kt * 32 + k8;
      avh = *(const uint4*)(h_hi_r + (size_t)(m0 + r) * KH + ka);
      avl = *(const uint4*)(h_lo_r + (size_t)(m0 + r) * KH + ka);
    } else {
      const int kx = (kt - KTH) * 32 + k8;
      const float* xrow = xt + (size_t)(m0 + r) * INPUT;
      float v[8];
      if (kx + 7 < INPUT) {
        float4 f0 = *(const float4*)(xrow + kx);
        float4 f1 = *(const float4*)(xrow + kx + 4);
        v[0] = f0.x; v[1] = f0.y; v[2] = f0.z; v[3] = f0.w;
        v[4] = f1.x; v[5] = f1.y; v[6] = f1.z; v[7] = f1.w;
      } else {
#pragma unroll
        for (int i = 0; i < 8; ++i) v[i] = (kx + i < INPUT) ? xrow[kx + i] : 0.f;
      }
      unsigned short hh[8], ll[8];
#pragma unroll
      for (int i = 0; i < 8; ++i) {
        hh[i] = bf16_rne(v[i]);
        ll[i] = bf16_rne(v[i] - bf16f(hh[i]));
      }
      avh.x = hh[0] | ((unsigned)hh[1] << 16); avh.y = hh[2] | ((unsigned)hh[3] << 16);
      avh.z = hh[4] | ((unsigned)hh[5] << 16); avh.w = hh[6] | ((unsigned)hh[7] << 16);
      avl.x = ll[0] | ((unsigned)ll[1] << 16); avl.y = ll[2] | ((unsigned)ll[3] << 16);
      avl.z = ll[4] | ((unsigned)ll[5] << 16); avl.w = ll[6] | ((unsigned)ll[7] << 16);
    }
    {
      const size_t boff = (size_t)(n0 + r) * KT + kt * 32 + k8;
      bvh = *(const uint4*)(Wph + boff);
      bvl = *(const uint4*)(Wpl + boff);
    }

    __syncthreads();   // previous iteration's fragment reads done
    *(uint4*)(sAh + r * 40 + k8) = avh;
    *(uint4*)(sAl + r * 40 + k8) = avl;
    *(uint4*)(sBh + r * 40 + k8) = bvh;
    *(uint4*)(sBl + r * 40 + k8) = bvl;
    __syncthreads();

    // ---- fragments + MFMA (3-way split: hi*hi + hi*lo + lo*hi) ----
    short8 ah[2], al[2], bh[2], bl[2];
#pragma unroll
    for (int mt = 0; mt < 2; ++mt) {
      const int row = (wm + mt * 16 + col) * 40 + quad * 8;
      ah[mt] = *(const short8*)(sAh + row);
      al[mt] = *(const short8*)(sAl + row);
    }
#pragma unroll
    for (int nt = 0; nt < 2; ++nt) {
      const int row = (wn + nt * 16 + col) * 40 + quad * 8;
      bh[nt] = *(const short8*)(sBh + row);
      bl[nt] = *(const short8*)(sBl + row);
    }
#pragma unroll
    for (int mt = 0; mt < 2; ++mt)
#pragma unroll
      for (int nt = 0; nt < 2; ++nt) {
        acc[mt][nt] = __builtin_amdgcn_mfma_f32_16x16x32_bf16(ah[mt], bh[nt], acc[mt][nt], 0, 0, 0);
        acc[mt][nt] = __builtin_amdgcn_mfma_f32_16x16x32_bf16(ah[mt], bl[nt], acc[mt][nt], 0, 0, 0);
        acc[mt][nt] = __builtin_amdgcn_mfma_f32_16x16x32_bf16(al[mt], bh[nt], acc[mt][nt], 0, 0, 0);
      }
  }

  // ---- epilogue: gates -> LDS [n'][m], then fused cell update ----
  __syncthreads();
  float* epi = (float*)sb;   // [64 n'][65 m] = 16640 floats... (64*65 floats = 16.6 KB <= 20.5 KB)
#pragma unroll
  for (int mt = 0; mt < 2; ++mt)
#pragma unroll
    for (int nt = 0; nt < 2; ++nt) {
      const int nl = wn + nt * 16 + col;
      const float bb = biasp[n0 + nl];
#pragma unroll
      for (int reg = 0; reg < 4; ++reg) {
        const int ml = wm + mt * 16 + quad * 4 + reg;
        epi[nl * 65 + ml] = acc[mt][nt][reg] + bb;
      }
    }
  __syncthreads();

  // cell: thread owns m = t>>2, j-local = (t&3)*4 .. +3
  const int mloc = t >> 2;
  const int jl4  = (t & 3) * 4;
  const int m    = m0 + mloc;
  float4 cold = *(const float4*)(cst + (size_t)m * HIDDEN + j0 + jl4);
  float cn[4], hn[4];
#pragma unroll
  for (int jj = 0; jj < 4; ++jj) {
    const int nl = (jl4 + jj) * 4;
    const float gi = epi[(nl + 0) * 65 + mloc];
    const float gf = epi[(nl + 1) * 65 + mloc];
    const float gg = epi[(nl + 2) * 65 + mloc];
    const float go = epi[(nl + 3) * 65 + mloc];
    const float cc = (jj == 0) ? cold.x : (jj == 1) ? cold.y : (jj == 2) ? cold.z : cold.w;
    const float cnew = sigf(gf) * cc + sigf(gi) * tanhfast(gg);
    cn[jj] = cnew;
    hn[jj] = sigf(go) * tanhfast(cnew);
  }
  *(float4*)(cst + (size_t)m * HIDDEN + j0 + jl4) = make_float4(cn[0], cn[1], cn[2], cn[3]);
  *(float4*)(h_f32 + (size_t)m * HIDDEN + j0 + jl4) = make_float4(hn[0], hn[1], hn[2], hn[3]);
  ushort4 uh, ul;
  uh.x = bf16_rne(hn[0]); uh.y = bf16_rne(hn[1]); uh.z = bf16_rne(hn[2]); uh.w = bf16_rne(hn[3]);
  ul.x = bf16_rne(hn[0] - bf16f(uh.x));
  ul.y = bf16_rne(hn[1] - bf16f(uh.y));
  ul.z = bf16_rne(hn[2] - bf16f(uh.z));
  ul.w = bf16_rne(hn[3] - bf16f(uh.w));
  *(ushort4*)(h_hi_w + (size_t)m * HIDDEN + j0 + jl4) = uh;
  *(ushort4*)(h_lo_w + (size_t)m * HIDDEN + j0 + jl4) = ul;
}

// ---------------- head: fp32 tiled GEMM C = A*B^T + bias (small, keep simple) ----------------
#define BK 16
#define LDP 68
__global__ __launch_bounds__(256) void gemm_bt(
    const float* __restrict__ Ah, int Kh_stride,
    const float* __restrict__ B2,
    const float* __restrict__ bias1,
    int Ktot, int N, float* __restrict__ C)
{
  __shared__ float sA[BK * LDP];
  __shared__ float sB[BK * LDP];
  const int t  = threadIdx.x;
  const int tx = t & 15;
  const int ty = t >> 4;
  const int r  = t >> 2;
  const int c4 = (t & 3) << 2;
  const int m0 = blockIdx.y * 64;
  const int n0 = blockIdx.x * 64;

  float acc[4][4] = {{0.f}};
  for (int k0 = 0; k0 < Ktot; k0 += BK) {
    const int k = k0 + c4;
    float4 av = *(const float4*)(Ah + (size_t)(m0 + r) * Kh_stride + k);
    float4 bv = *(const float4*)(B2 + (size_t)(n0 + r) * Kh_stride + k);
    __syncthreads();
    sA[(c4 + 0) * LDP + r] = av.x; sA[(c4 + 1) * LDP + r] = av.y;
    sA[(c4 + 2) * LDP + r] = av.z; sA[(c4 + 3) * LDP + r] = av.w;
    sB[(c4 + 0) * LDP + r] = bv.x; sB[(c4 + 1) * LDP + r] = bv.y;
    sB[(c4 + 2) * LDP + r] = bv.z; sB[(c4 + 3) * LDP + r] = bv.w;
    __syncthreads();
#pragma unroll
    for (int kk = 0; kk < BK; ++kk) {
      const float4 a = *(const float4*)&sA[kk * LDP + ty * 4];
      const float4 b = *(const float4*)&sB[kk * LDP + tx * 4];
      acc[0][0] += a.x * b.x; acc[0][1] += a.x * b.y; acc[0][2] += a.x * b.z; acc[0][3] += a.x * b.w;
      acc[1][0] += a.y * b.x; acc[1][1] += a.y * b.y; acc[1][2] += a.y * b.z; acc[1][3] += a.y * b.w;
      acc[2][0] += a.z * b.x; acc[2][1] += a.z * b.y; acc[2][2] += a.z * b.z; acc[2][3] += a.z * b.w;
      acc[3][0] += a.w * b.x; acc[3][1] += a.w * b.y; acc[3][2] += a.w * b.z; acc[3][3] += a.w * b.w;
    }
  }
#pragma unroll
  for (int i = 0; i < 4; ++i) {
    const int m = m0 + ty * 4 + i;
    float4 o;
    o.x = acc[i][0] + bias1[n0 + tx * 4 + 0];
    o.y = acc[i][1] + bias1[n0 + tx * 4 + 1];
    o.z = acc[i][2] + bias1[n0 + tx * 4 + 2];
    o.w = acc[i][3] + bias1[n0 + tx * 4 + 3];
    *(float4*)(C + (size_t)m * N + n0 + tx * 4) = o;
  }
}

// ---------------- BN stats ----------------
__global__ __launch_bounds__(64) void bn_stats(
    const float* __restrict__ z, float* __restrict__ mean, float* __restrict__ rstd)
{
  const int n = blockIdx.x;
  const int t = threadIdx.x;
  float s = 0.f, s2 = 0.f;
  for (int r = t; r < BATCH; r += 64) {
    const float v = z[(size_t)r * LINEARN + n];
    s += v; s2 += v * v;
  }
#pragma unroll
  for (int off = 32; off > 0; off >>= 1) {
    s  += __shfl_down(s,  off, 64);
    s2 += __shfl_down(s2, off, 64);
  }
  if (t == 0) {
    const float m = s * (1.f / BATCH);
    mean[n] = m;
    rstd[n] = rsqrtf(s2 * (1.f / BATCH) - m * m + 1e-5f);
  }
}

// ---------------- head out ----------------
__global__ __launch_bounds__(256) void head_out(
    const float* __restrict__ z, const float* __restrict__ mean, const float* __restrict__ rstd,
    const float* __restrict__ gamma, const float* __restrict__ beta,
    const float* __restrict__ W2, const float* __restrict__ b2, float* __restrict__ out)
{
  const int b = blockIdx.x;
  const int t = threadIdx.x;
  float acc = 0.f;
  for (int n = t; n < LINEARN; n += 256) {
    float v = (z[(size_t)b * LINEARN + n] - mean[n]) * rstd[n] * gamma[n] + beta[n];
    v = fmaxf(v, 0.f);
    acc += v * W2[n];
  }
#pragma unroll
  for (int off = 32; off > 0; off >>= 1) acc += __shfl_down(acc, off, 64);
  __shared__ float ls[4];
  if ((t & 63) == 0) ls[t >> 6] = acc;
  __syncthreads();
  if (t == 0) {
    const float tot = ls[0] + ls[1] + ls[2] + ls[3] + b2[0];
    out[b] = 3.f / (1.f + __expf(-tot));
  }
}

// ---------------- launch ----------------
extern "C" void kernel_launch(void* const* d_in, const int* in_sizes, int n_in,
                              void* d_out, int out_size, void* d_ws, size_t ws_size,
                              hipStream_t stream) {
  const float* x     = (const float*)d_in[0];
  const float* W_ih  = (const float*)d_in[1];
  const float* W_hh  = (const float*)d_in[2];
  const float* b_ih  = (const float*)d_in[3];
  const float* b_hh  = (const float*)d_in[4];
  const float* W1    = (const float*)d_in[5];
  const float* b1    = (const float*)d_in[6];
  const float* gamma = (const float*)d_in[7];
  const float* beta  = (const float*)d_in[8];
  const float* W2    = (const float*)d_in[9];
  const float* b2    = (const float*)d_in[10];
  float* out = (float*)d_out;

  char* w = (char*)d_ws;
  // zero region (must stay contiguous): h_hi0, h_lo0, c  = 2 MB
  unsigned short* h_hi0 = (unsigned short*)(w + 0);
  unsigned short* h_lo0 = (unsigned short*)(w + 524288);
  float*          cst   = (float*)(w + 1048576);
  unsigned short* h_hi1 = (unsigned short*)(w + 2097152);
  unsigned short* h_lo1 = (unsigned short*)(w + 2621440);
  unsigned short* Wph   = (unsigned short*)(w + 3145728);
  unsigned short* Wpl   = (unsigned short*)(w + 14155776);
  float*          biasp = (float*)(w + 25165824);
  float*          h_f32 = (float*)(w + 25182208);
  float*          z     = (float*)(w + 26230784);
  float*          mean  = (float*)(w + 27279360);
  float*          rstd  = (float*)(w + 27283456);

  zero_ws<<<512, 256, 0, stream>>>((float4*)w, 131072);                 // 2 MB: h0 hi/lo + c
  pack_w<<<(NG * KT + 255) / 256, 256, 0, stream>>>(W_ih, W_hh, Wph, Wpl);
  pack_bias<<<NG / 256, 256, 0, stream>>>(b_ih, b_hh, biasp);

  for (int t = 0; t < SEQ; ++t) {
    const float* xt = x + (size_t)t * BATCH * INPUT;
    const unsigned short* hr_hi = (t & 1) ? h_hi1 : h_hi0;
    const unsigned short* hr_lo = (t & 1) ? h_lo1 : h_lo0;
    unsigned short* hw_hi = (t & 1) ? h_hi0 : h_hi1;
    unsigned short* hw_lo = (t & 1) ? h_lo0 : h_lo1;
    lstm_step<<<dim3(64, 4), 256, 0, stream>>>(
        xt, hr_hi, hr_lo, Wph, Wpl, biasp, cst, hw_hi, hw_lo, h_f32);
  }

  gemm_bt<<<dim3(LINEARN / 64, BATCH / 64), 256, 0, stream>>>(
      h_f32, HIDDEN, W1, b1, HIDDEN, LINEARN, z);
  bn_stats<<<LINEARN, 64, 0, stream>>>(z, mean, rstd);
  head_out<<<BATCH, 256, 0, stream>>>(z, mean, rstd, gamma, beta, W2, b2, out);
}

// Round 3
// 2803.086 us; speedup vs baseline: 4.0114x; 1.5504x over previous
//
#include <hip/hip_runtime.h>
#include <math.h>

// ---------------- constants ----------------
#define SEQ 128
#define BATCH 256
#define INPUT 300
#define HIDDEN 1024
#define NG 4096              // 4*HIDDEN, gate-interleaved: n' = 4*j + gate
#define KH 1024              // h part of K (first)
#define KXP 320              // x part padded 300->320
#define KT 1344              // KH + KXP
#define NKT 42               // KT/32 k-tiles
#define KTH 32               // KH/32 k-tiles from h
#define NKTH 32              // head k-tiles (K=1024)
#define LINEARN 1024

typedef __attribute__((ext_vector_type(8))) short short8;
typedef __attribute__((ext_vector_type(4))) float floatx4;

__device__ __forceinline__ float sigf(float x)     { return 1.f / (1.f + __expf(-x)); }
__device__ __forceinline__ float tanhfast(float x) { return 2.f / (1.f + __expf(-2.f * x)) - 1.f; }

__device__ __forceinline__ unsigned short bf16_rne(float f) {
  unsigned u = __float_as_uint(f);
  u += 0x7FFFu + ((u >> 16) & 1u);
  return (unsigned short)(u >> 16);
}
__device__ __forceinline__ float bf16f(unsigned short s) {
  return __uint_as_float(((unsigned)s) << 16);
}

// ---------------- zero ----------------
__global__ __launch_bounds__(256) void zero_ws(float4* p, int n4) {
  int i = blockIdx.x * 256 + threadIdx.x;
  if (i < n4) p[i] = make_float4(0.f, 0.f, 0.f, 0.f);
}

// ---------------- weight pack: gate-interleave + pad + bf16 hi/lo split ----------------
__global__ __launch_bounds__(256) void pack_w(
    const float* __restrict__ W_ih, const float* __restrict__ W_hh,
    unsigned short* __restrict__ Wph, unsigned short* __restrict__ Wpl)
{
  int id = blockIdx.x * 256 + threadIdx.x;
  if (id >= NG * KT) return;
  int n = id / KT;
  int k = id - n * KT;
  int j = n >> 2, g = n & 3;
  int srow = g * HIDDEN + j;
  float w = 0.f;
  if (k < KH) w = W_hh[(size_t)srow * HIDDEN + k];
  else if (k - KH < INPUT) w = W_ih[(size_t)srow * INPUT + (k - KH)];
  unsigned short hi = bf16_rne(w);
  Wph[id] = hi;
  Wpl[id] = bf16_rne(w - bf16f(hi));
}

__global__ __launch_bounds__(256) void pack_bias(
    const float* __restrict__ b_ih, const float* __restrict__ b_hh,
    float* __restrict__ biasp)
{
  int n = blockIdx.x * 256 + threadIdx.x;
  if (n >= NG) return;
  int j = n >> 2, g = n & 3;
  int s = g * HIDDEN + j;
  biasp[n] = b_ih[s] + b_hh[s];
}

// ---------------- pack all x timesteps to bf16 hi/lo, padded 300->320 ----------------
__global__ __launch_bounds__(256) void pack_x(
    const float* __restrict__ x, unsigned short* __restrict__ xph,
    unsigned short* __restrict__ xpl)
{
  int id = blockIdx.x * 256 + threadIdx.x;        // over 32768*320
  if (id >= SEQ * BATCH * KXP) return;
  int row = id / KXP;
  int k = id - row * KXP;
  float v = (k < INPUT) ? x[(size_t)row * INPUT + k] : 0.f;
  unsigned short hi = bf16_rne(v);
  xph[id] = hi;
  xpl[id] = bf16_rne(v - bf16f(hi));
}

// ---------------- pack W1 (head) hi/lo ----------------
__global__ __launch_bounds__(256) void pack_w1(
    const float* __restrict__ W1, unsigned short* __restrict__ W1ph,
    unsigned short* __restrict__ W1pl)
{
  int id = blockIdx.x * 256 + threadIdx.x;        // over 1024*1024
  if (id >= LINEARN * HIDDEN) return;
  float w = W1[id];
  unsigned short hi = bf16_rne(w);
  W1ph[id] = hi;
  W1pl[id] = bf16_rne(w - bf16f(hi));
}

// ---------------- fused LSTM step: pipelined split-bf16 MFMA GEMM + cell ----------------
// grid (64 jtiles, 4 mtiles), 256 threads. Tile 64x64, wave tile 32x32 (2x2 of 16x16x32).
// Depth-2 register prefetch + double-buffered LDS, one barrier per k-tile.
__global__ __launch_bounds__(256) void lstm_step(
    const unsigned short* __restrict__ xp_hi,   // [256][320] this step
    const unsigned short* __restrict__ xp_lo,
    const unsigned short* __restrict__ h_hi_r,  // [256][1024]
    const unsigned short* __restrict__ h_lo_r,
    const unsigned short* __restrict__ Wph,     // [4096][1344]
    const unsigned short* __restrict__ Wpl,
    const float* __restrict__ biasp,            // [4096]
    float* __restrict__ cst,                    // [256][1024] fp32 cell state
    unsigned short* __restrict__ h_hi_w,
    unsigned short* __restrict__ h_lo_w)
{
  __shared__ short sb[2 * 4 * 2560];    // 40 KB: 2 bufs x {Ah,Al,Bh,Bl} x 64rows x 40stride

  const int t    = threadIdx.x;
  const int lane = t & 63;
  const int wave = t >> 6;
  const int wm   = (wave >> 1) * 32;
  const int wn   = (wave & 1) * 32;
  const int col  = lane & 15;
  const int quad = lane >> 4;
  const int r    = t >> 2;              // staging row 0..63
  const int k8   = (t & 3) * 8;         // staging k offset {0,8,16,24} (shorts)
  const int m0   = blockIdx.y * 64;
  const int n0   = blockIdx.x * 64;
  const int j0   = blockIdx.x * 16;

#define LOAD_TILE(kt, AH, AL, BH, BL) do {                                   \
    if ((kt) < KTH) {                                                        \
      const int ka = (kt) * 32 + k8;                                         \
      AH = *(const uint4*)(h_hi_r + (size_t)(m0 + r) * KH + ka);             \
      AL = *(const uint4*)(h_lo_r + (size_t)(m0 + r) * KH + ka);             \
    } else {                                                                 \
      const int kx = ((kt) - KTH) * 32 + k8;                                 \
      AH = *(const uint4*)(xp_hi + (size_t)(m0 + r) * KXP + kx);             \
      AL = *(const uint4*)(xp_lo + (size_t)(m0 + r) * KXP + kx);             \
    }                                                                        \
    { const size_t bo = (size_t)(n0 + r) * KT + (kt) * 32 + k8;              \
      BH = *(const uint4*)(Wph + bo);                                        \
      BL = *(const uint4*)(Wpl + bo); }                                      \
  } while (0)

#define STORE_TILE(base, AH, AL, BH, BL) do {                                \
    *(uint4*)((base) +        r * 40 + k8) = AH;                             \
    *(uint4*)((base) + 2560 + r * 40 + k8) = AL;                             \
    *(uint4*)((base) + 5120 + r * 40 + k8) = BH;                             \
    *(uint4*)((base) + 7680 + r * 40 + k8) = BL;                             \
  } while (0)

  floatx4 acc[2][2];
#pragma unroll
  for (int i = 0; i < 2; ++i)
#pragma unroll
    for (int jj = 0; jj < 2; ++jj)
      acc[i][jj] = (floatx4){0.f, 0.f, 0.f, 0.f};

  uint4 cAh, cAl, cBh, cBl, nAh, nAl, nBh, nBl, tAh, tAl, tBh, tBl;
  // prologue: tile0 -> buf0; tile1 -> cur regs
  LOAD_TILE(0, tAh, tAl, tBh, tBl);
  LOAD_TILE(1, cAh, cAl, cBh, cBl);
  STORE_TILE(sb, tAh, tAl, tBh, tBl);

  for (int kt = 0; kt < NKT; ++kt) {
    if (kt + 2 < NKT) LOAD_TILE(kt + 2, nAh, nAl, nBh, nBl);
    __syncthreads();                       // publish buf[kt&1]
    short* bufp = sb + (kt & 1) * 10240;

    short8 ah[2], al[2], bh[2], bl[2];
#pragma unroll
    for (int mt = 0; mt < 2; ++mt) {
      const int row = (wm + mt * 16 + col) * 40 + quad * 8;
      ah[mt] = *(const short8*)(bufp + row);
      al[mt] = *(const short8*)(bufp + 2560 + row);
    }
#pragma unroll
    for (int nt = 0; nt < 2; ++nt) {
      const int row = (wn + nt * 16 + col) * 40 + quad * 8;
      bh[nt] = *(const short8*)(bufp + 5120 + row);
      bl[nt] = *(const short8*)(bufp + 7680 + row);
    }
#pragma unroll
    for (int mt = 0; mt < 2; ++mt)
#pragma unroll
      for (int nt = 0; nt < 2; ++nt) {
        acc[mt][nt] = __builtin_amdgcn_mfma_f32_16x16x32_bf16(ah[mt], bh[nt], acc[mt][nt], 0, 0, 0);
        acc[mt][nt] = __builtin_amdgcn_mfma_f32_16x16x32_bf16(ah[mt], bl[nt], acc[mt][nt], 0, 0, 0);
        acc[mt][nt] = __builtin_amdgcn_mfma_f32_16x16x32_bf16(al[mt], bh[nt], acc[mt][nt], 0, 0, 0);
      }

    if (kt + 1 < NKT) STORE_TILE(sb + ((kt + 1) & 1) * 10240, cAh, cAl, cBh, cBl);
    cAh = nAh; cAl = nAl; cBh = nBh; cBl = nBl;
  }

  // ---- epilogue: gates -> LDS [n'][m], then fused cell update ----
  __syncthreads();
  float* epi = (float*)sb;   // 64*65 floats = 16.6 KB <= 40 KB
#pragma unroll
  for (int mt = 0; mt < 2; ++mt)
#pragma unroll
    for (int nt = 0; nt < 2; ++nt) {
      const int nl = wn + nt * 16 + col;
      const float bb = biasp[n0 + nl];
#pragma unroll
      for (int reg = 0; reg < 4; ++reg) {
        const int ml = wm + mt * 16 + quad * 4 + reg;
        epi[nl * 65 + ml] = acc[mt][nt][reg] + bb;
      }
    }
  __syncthreads();

  const int mloc = t >> 2;
  const int jl4  = (t & 3) * 4;
  const int m    = m0 + mloc;
  float4 cold = *(const float4*)(cst + (size_t)m * HIDDEN + j0 + jl4);
  float cn[4], hn[4];
#pragma unroll
  for (int jj = 0; jj < 4; ++jj) {
    const int nl = (jl4 + jj) * 4;
    const float gi = epi[(nl + 0) * 65 + mloc];
    const float gf = epi[(nl + 1) * 65 + mloc];
    const float gg = epi[(nl + 2) * 65 + mloc];
    const float go = epi[(nl + 3) * 65 + mloc];
    const float cc = (jj == 0) ? cold.x : (jj == 1) ? cold.y : (jj == 2) ? cold.z : cold.w;
    const float cnew = sigf(gf) * cc + sigf(gi) * tanhfast(gg);
    cn[jj] = cnew;
    hn[jj] = sigf(go) * tanhfast(cnew);
  }
  *(float4*)(cst + (size_t)m * HIDDEN + j0 + jl4) = make_float4(cn[0], cn[1], cn[2], cn[3]);
  ushort4 uh, ul;
  uh.x = bf16_rne(hn[0]); uh.y = bf16_rne(hn[1]); uh.z = bf16_rne(hn[2]); uh.w = bf16_rne(hn[3]);
  ul.x = bf16_rne(hn[0] - bf16f(uh.x));
  ul.y = bf16_rne(hn[1] - bf16f(uh.y));
  ul.z = bf16_rne(hn[2] - bf16f(uh.z));
  ul.w = bf16_rne(hn[3] - bf16f(uh.w));
  *(ushort4*)(h_hi_w + (size_t)m * HIDDEN + j0 + jl4) = uh;
  *(ushort4*)(h_lo_w + (size_t)m * HIDDEN + j0 + jl4) = ul;
#undef LOAD_TILE
#undef STORE_TILE
}

// ---------------- head GEMM: z = h @ W1^T + b1, same pipelined MFMA ----------------
__global__ __launch_bounds__(256) void head_gemm(
    const unsigned short* __restrict__ Ah_,     // h_hi [256][1024]
    const unsigned short* __restrict__ Al_,
    const unsigned short* __restrict__ Bh_,     // W1 hi [1024][1024]
    const unsigned short* __restrict__ Bl_,
    const float* __restrict__ bias,             // b1
    float* __restrict__ C)                      // z [256][1024]
{
  __shared__ short sb[2 * 4 * 2560];

  const int t    = threadIdx.x;
  const int lane = t & 63;
  const int wave = t >> 6;
  const int wm   = (wave >> 1) * 32;
  const int wn   = (wave & 1) * 32;
  const int col  = lane & 15;
  const int quad = lane >> 4;
  const int r    = t >> 2;
  const int k8   = (t & 3) * 8;
  const int m0   = blockIdx.y * 64;
  const int n0   = blockIdx.x * 64;

#define LOAD_TILE(kt, AH, AL, BH, BL) do {                                   \
    const int ka = (kt) * 32 + k8;                                           \
    AH = *(const uint4*)(Ah_ + (size_t)(m0 + r) * KH + ka);                  \
    AL = *(const uint4*)(Al_ + (size_t)(m0 + r) * KH + ka);                  \
    BH = *(const uint4*)(Bh_ + (size_t)(n0 + r) * KH + ka);                  \
    BL = *(const uint4*)(Bl_ + (size_t)(n0 + r) * KH + ka);                  \
  } while (0)

#define STORE_TILE(base, AH, AL, BH, BL) do {                                \
    *(uint4*)((base) +        r * 40 + k8) = AH;                             \
    *(uint4*)((base) + 2560 + r * 40 + k8) = AL;                             \
    *(uint4*)((base) + 5120 + r * 40 + k8) = BH;                             \
    *(uint4*)((base) + 7680 + r * 40 + k8) = BL;                             \
  } while (0)

  floatx4 acc[2][2];
#pragma unroll
  for (int i = 0; i < 2; ++i)
#pragma unroll
    for (int jj = 0; jj < 2; ++jj)
      acc[i][jj] = (floatx4){0.f, 0.f, 0.f, 0.f};

  uint4 cAh, cAl, cBh, cBl, nAh, nAl, nBh, nBl, tAh, tAl, tBh, tBl;
  LOAD_TILE(0, tAh, tAl, tBh, tBl);
  LOAD_TILE(1, cAh, cAl, cBh, cBl);
  STORE_TILE(sb, tAh, tAl, tBh, tBl);

  for (int kt = 0; kt < NKTH; ++kt) {
    if (kt + 2 < NKTH) LOAD_TILE(kt + 2, nAh, nAl, nBh, nBl);
    __syncthreads();
    short* bufp = sb + (kt & 1) * 10240;

    short8 ah[2], al[2], bh[2], bl[2];
#pragma unroll
    for (int mt = 0; mt < 2; ++mt) {
      const int row = (wm + mt * 16 + col) * 40 + quad * 8;
      ah[mt] = *(const short8*)(bufp + row);
      al[mt] = *(const short8*)(bufp + 2560 + row);
    }
#pragma unroll
    for (int nt = 0; nt < 2; ++nt) {
      const int row = (wn + nt * 16 + col) * 40 + quad * 8;
      bh[nt] = *(const short8*)(bufp + 5120 + row);
      bl[nt] = *(const short8*)(bufp + 7680 + row);
    }
#pragma unroll
    for (int mt = 0; mt < 2; ++mt)
#pragma unroll
      for (int nt = 0; nt < 2; ++nt) {
        acc[mt][nt] = __builtin_amdgcn_mfma_f32_16x16x32_bf16(ah[mt], bh[nt], acc[mt][nt], 0, 0, 0);
        acc[mt][nt] = __builtin_amdgcn_mfma_f32_16x16x32_bf16(ah[mt], bl[nt], acc[mt][nt], 0, 0, 0);
        acc[mt][nt] = __builtin_amdgcn_mfma_f32_16x16x32_bf16(al[mt], bh[nt], acc[mt][nt], 0, 0, 0);
      }

    if (kt + 1 < NKTH) STORE_TILE(sb + ((kt + 1) & 1) * 10240, cAh, cAl, cBh, cBl);
    cAh = nAh; cAl = nAl; cBh = nBh; cBl = nBl;
  }

#pragma unroll
  for (int mt = 0; mt < 2; ++mt)
#pragma unroll
    for (int nt = 0; nt < 2; ++nt) {
      const int nl = n0 + wn + nt * 16 + col;
      const float bb = bias[nl];
#pragma unroll
      for (int reg = 0; reg < 4; ++reg) {
        const int ml = m0 + wm + mt * 16 + quad * 4 + reg;
        C[(size_t)ml * LINEARN + nl] = acc[mt][nt][reg] + bb;
      }
    }
#undef LOAD_TILE
#undef STORE_TILE
}

// ---------------- BN stats ----------------
__global__ __launch_bounds__(64) void bn_stats(
    const float* __restrict__ z, float* __restrict__ mean, float* __restrict__ rstd)
{
  const int n = blockIdx.x;
  const int t = threadIdx.x;
  float s = 0.f, s2 = 0.f;
  for (int r = t; r < BATCH; r += 64) {
    const float v = z[(size_t)r * LINEARN + n];
    s += v; s2 += v * v;
  }
#pragma unroll
  for (int off = 32; off > 0; off >>= 1) {
    s  += __shfl_down(s,  off, 64);
    s2 += __shfl_down(s2, off, 64);
  }
  if (t == 0) {
    const float m = s * (1.f / BATCH);
    mean[n] = m;
    rstd[n] = rsqrtf(s2 * (1.f / BATCH) - m * m + 1e-5f);
  }
}

// ---------------- head out ----------------
__global__ __launch_bounds__(256) void head_out(
    const float* __restrict__ z, const float* __restrict__ mean, const float* __restrict__ rstd,
    const float* __restrict__ gamma, const float* __restrict__ beta,
    const float* __restrict__ W2, const float* __restrict__ b2, float* __restrict__ out)
{
  const int b = blockIdx.x;
  const int t = threadIdx.x;
  float acc = 0.f;
  for (int n = t; n < LINEARN; n += 256) {
    float v = (z[(size_t)b * LINEARN + n] - mean[n]) * rstd[n] * gamma[n] + beta[n];
    v = fmaxf(v, 0.f);
    acc += v * W2[n];
  }
#pragma unroll
  for (int off = 32; off > 0; off >>= 1) acc += __shfl_down(acc, off, 64);
  __shared__ float ls[4];
  if ((t & 63) == 0) ls[t >> 6] = acc;
  __syncthreads();
  if (t == 0) {
    const float tot = ls[0] + ls[1] + ls[2] + ls[3] + b2[0];
    out[b] = 3.f / (1.f + __expf(-tot));
  }
}

// ---------------- launch ----------------
extern "C" void kernel_launch(void* const* d_in, const int* in_sizes, int n_in,
                              void* d_out, int out_size, void* d_ws, size_t ws_size,
                              hipStream_t stream) {
  const float* x     = (const float*)d_in[0];
  const float* W_ih  = (const float*)d_in[1];
  const float* W_hh  = (const float*)d_in[2];
  const float* b_ih  = (const float*)d_in[3];
  const float* b_hh  = (const float*)d_in[4];
  const float* W1    = (const float*)d_in[5];
  const float* b1    = (const float*)d_in[6];
  const float* gamma = (const float*)d_in[7];
  const float* beta  = (const float*)d_in[8];
  const float* W2    = (const float*)d_in[9];
  const float* b2    = (const float*)d_in[10];
  float* out = (float*)d_out;

  char* w = (char*)d_ws;
  // zero region (contiguous 2 MB): h_hi0, h_lo0, c
  unsigned short* h_hi0 = (unsigned short*)(w + 0);
  unsigned short* h_lo0 = (unsigned short*)(w + 524288);
  float*          cst   = (float*)(w + 1048576);
  unsigned short* h_hi1 = (unsigned short*)(w + 2097152);
  unsigned short* h_lo1 = (unsigned short*)(w + 2621440);
  unsigned short* Wph   = (unsigned short*)(w + 3145728);    // 11,010,048 B
  unsigned short* Wpl   = (unsigned short*)(w + 14155776);   // 11,010,048 B
  float*          biasp = (float*)(w + 25165824);            // 16 KB
  unsigned short* xph   = (unsigned short*)(w + 25182208);   // 20,971,520 B
  unsigned short* xpl   = (unsigned short*)(w + 46153728);   // 20,971,520 B
  unsigned short* W1ph  = (unsigned short*)(w + 67125248);   // 2 MB
  unsigned short* W1pl  = (unsigned short*)(w + 69222400);   // 2 MB
  float*          z     = (float*)(w + 71319552);            // 1 MB
  float*          mean  = (float*)(w + 72368128);
  float*          rstd  = (float*)(w + 72372224);

  zero_ws<<<512, 256, 0, stream>>>((float4*)w, 131072);
  pack_w<<<(NG * KT + 255) / 256, 256, 0, stream>>>(W_ih, W_hh, Wph, Wpl);
  pack_bias<<<NG / 256, 256, 0, stream>>>(b_ih, b_hh, biasp);
  pack_x<<<(SEQ * BATCH * KXP + 255) / 256, 256, 0, stream>>>(x, xph, xpl);
  pack_w1<<<(LINEARN * HIDDEN + 255) / 256, 256, 0, stream>>>(W1, W1ph, W1pl);

  for (int t = 0; t < SEQ; ++t) {
    const unsigned short* hr_hi = (t & 1) ? h_hi1 : h_hi0;
    const unsigned short* hr_lo = (t & 1) ? h_lo1 : h_lo0;
    unsigned short* hw_hi = (t & 1) ? h_hi0 : h_hi1;
    unsigned short* hw_lo = (t & 1) ? h_lo0 : h_lo1;
    lstm_step<<<dim3(64, 4), 256, 0, stream>>>(
        xph + (size_t)t * BATCH * KXP, xpl + (size_t)t * BATCH * KXP,
        hr_hi, hr_lo, Wph, Wpl, biasp, cst, hw_hi, hw_lo);
  }

  // final h is in h_hi0/h_lo0 (last write at t=127, odd)
  head_gemm<<<dim3(LINEARN / 64, BATCH / 64), 256, 0, stream>>>(
      h_hi0, h_lo0, W1ph, W1pl, b1, z);
  bn_stats<<<LINEARN, 64, 0, stream>>>(z, mean, rstd);
  head_out<<<BATCH, 256, 0, stream>>>(z, mean, rstd, gamma, beta, W2, b2, out);
}